// Round 1
// baseline (4208.746 us; speedup 1.0000x reference)
//
#include <hip/hip_runtime.h>
#include <stdint.h>

// PointNet EdgeConv, 2 layers:
//   layer(h): per-edge e=(src,dst): m = relu(concat(h[src], pos[src]-pos[dst]) @ Wa + ba) @ Wb + bb
//             agg = segment_max(m, dst); out = relu(where(finite, agg, 0)) == fmaxf(agg, 0)
// Strategy: thread-per-edge fused MLP (weights in LDS, float4 broadcast reads),
// scatter-max via atomicMax on order-preserving uint32 encoding of fp32.

#define N_HIDDEN 32

__device__ __forceinline__ unsigned ordenc(float f) {
    unsigned u = __float_as_uint(f);
    return (u & 0x80000000u) ? ~u : (u | 0x80000000u);
}
__device__ __forceinline__ float orddec(unsigned o) {
    unsigned u = (o & 0x80000000u) ? (o ^ 0x80000000u) : ~o;
    return __uint_as_float(u);
}

#define ORD_NEG_INF 0x007FFFFFu  // ordenc(-inf)

__global__ __launch_bounds__(256) void init_agg_kernel(unsigned* __restrict__ a,
                                                       unsigned* __restrict__ b, int n) {
    int i = blockIdx.x * 256 + threadIdx.x;
    if (i < n) {
        a[i] = ORD_NEG_INF;
        b[i] = ORD_NEG_INF;
    }
}

// In-place: decode ordered-uint max, apply relu (also maps -inf from isolated nodes to 0).
__global__ __launch_bounds__(256) void finalize_kernel(unsigned* __restrict__ buf, int n) {
    int i = blockIdx.x * 256 + threadIdx.x;
    if (i < n) {
        float v = orddec(buf[i]);
        reinterpret_cast<float*>(buf)[i] = fmaxf(v, 0.0f);
    }
}

// IN_DIM = 6 (layer 1: feat = [pos_src, rel]) or 35 (layer 2: feat = [h1_src, rel])
template <int IN_DIM>
__global__ __launch_bounds__(256) void edge_kernel(
    const float* __restrict__ pos, const int* __restrict__ ei, int E,
    const float* __restrict__ hsrc,  // node features for layer 2 (nullptr for layer 1)
    const float* __restrict__ Wa, const float* __restrict__ ba,
    const float* __restrict__ Wb, const float* __restrict__ bb,
    unsigned* __restrict__ agg) {
    __shared__ float sWa[IN_DIM * 32];
    __shared__ float sba[32];
    __shared__ float sWb[32 * 32];
    __shared__ float sbb[32];

    const int tid = threadIdx.x;
    for (int i = tid; i < IN_DIM * 32; i += 256) sWa[i] = Wa[i];
    for (int i = tid; i < 32 * 32; i += 256) sWb[i] = Wb[i];
    if (tid < 32) {
        sba[tid] = ba[tid];
        sbb[tid] = bb[tid];
    }
    __syncthreads();

    const int e = blockIdx.x * 256 + tid;
    if (e >= E) return;

    const int src = ei[e];
    const int dst = ei[E + e];

    const float psx = pos[src * 3 + 0];
    const float psy = pos[src * 3 + 1];
    const float psz = pos[src * 3 + 2];
    const float pdx = pos[dst * 3 + 0];
    const float pdy = pos[dst * 3 + 1];
    const float pdz = pos[dst * 3 + 2];

    float feat[IN_DIM];
    if constexpr (IN_DIM == 6) {
        feat[0] = psx;
        feat[1] = psy;
        feat[2] = psz;
        feat[3] = psx - pdx;
        feat[4] = psy - pdy;
        feat[5] = psz - pdz;
    } else {
        const float4* hp = reinterpret_cast<const float4*>(hsrc + (size_t)src * 32);
#pragma unroll
        for (int q = 0; q < 8; ++q) {
            float4 v = hp[q];
            feat[q * 4 + 0] = v.x;
            feat[q * 4 + 1] = v.y;
            feat[q * 4 + 2] = v.z;
            feat[q * 4 + 3] = v.w;
        }
        feat[32] = psx - pdx;
        feat[33] = psy - pdy;
        feat[34] = psz - pdz;
    }

    // hidden = relu(feat @ Wa + ba)
    float hid[32];
#pragma unroll
    for (int f4 = 0; f4 < 8; ++f4) {
        float4 acc = *reinterpret_cast<const float4*>(&sba[f4 * 4]);
#pragma unroll
        for (int i = 0; i < IN_DIM; ++i) {
            float4 w = *reinterpret_cast<const float4*>(&sWa[i * 32 + f4 * 4]);
            acc.x = fmaf(feat[i], w.x, acc.x);
            acc.y = fmaf(feat[i], w.y, acc.y);
            acc.z = fmaf(feat[i], w.z, acc.z);
            acc.w = fmaf(feat[i], w.w, acc.w);
        }
        hid[f4 * 4 + 0] = fmaxf(acc.x, 0.0f);
        hid[f4 * 4 + 1] = fmaxf(acc.y, 0.0f);
        hid[f4 * 4 + 2] = fmaxf(acc.z, 0.0f);
        hid[f4 * 4 + 3] = fmaxf(acc.w, 0.0f);
    }

    // out = hidden @ Wb + bb ; scatter-max into agg[dst]
    unsigned* abase = agg + (size_t)dst * 32;
#pragma unroll
    for (int k4 = 0; k4 < 8; ++k4) {
        float4 acc = *reinterpret_cast<const float4*>(&sbb[k4 * 4]);
#pragma unroll
        for (int h = 0; h < 32; ++h) {
            float4 w = *reinterpret_cast<const float4*>(&sWb[h * 32 + k4 * 4]);
            acc.x = fmaf(hid[h], w.x, acc.x);
            acc.y = fmaf(hid[h], w.y, acc.y);
            acc.z = fmaf(hid[h], w.z, acc.z);
            acc.w = fmaf(hid[h], w.w, acc.w);
        }
        atomicMax(abase + k4 * 4 + 0, ordenc(acc.x));
        atomicMax(abase + k4 * 4 + 1, ordenc(acc.y));
        atomicMax(abase + k4 * 4 + 2, ordenc(acc.z));
        atomicMax(abase + k4 * 4 + 3, ordenc(acc.w));
    }
}

extern "C" void kernel_launch(void* const* d_in, const int* in_sizes, int n_in,
                              void* d_out, int out_size, void* d_ws, size_t ws_size,
                              hipStream_t stream) {
    const float* pos = (const float*)d_in[0];
    const int* ei = (const int*)d_in[1];
    // d_in[2] = batch (unused; single graph)
    const float* W1 = (const float*)d_in[3];
    const float* b1 = (const float*)d_in[4];
    const float* W2 = (const float*)d_in[5];
    const float* b2 = (const float*)d_in[6];
    const float* W3 = (const float*)d_in[7];
    const float* b3 = (const float*)d_in[8];
    const float* W4 = (const float*)d_in[9];
    const float* b4 = (const float*)d_in[10];

    const int E = in_sizes[1] / 2;
    const int N = in_sizes[0] / 3;
    const int n32 = N * N_HIDDEN;

    unsigned* aggA = (unsigned*)d_ws;   // layer-1 agg, then (in place) h1 as float
    unsigned* aggB = (unsigned*)d_out;  // layer-2 agg, then (in place) final output

    const int gridN = (n32 + 255) / 256;
    const int gridE = (E + 255) / 256;

    init_agg_kernel<<<gridN, 256, 0, stream>>>(aggA, aggB, n32);
    edge_kernel<6><<<gridE, 256, 0, stream>>>(pos, ei, E, nullptr, W1, b1, W2, b2, aggA);
    finalize_kernel<<<gridN, 256, 0, stream>>>(aggA, n32);
    edge_kernel<35><<<gridE, 256, 0, stream>>>(pos, ei, E, (const float*)d_ws, W3, b3, W4, b4,
                                               aggB);
    finalize_kernel<<<gridN, 256, 0, stream>>>(aggB, n32);
}